// Round 14
// baseline (343.481 us; speedup 1.0000x reference)
//
#include <hip/hip_runtime.h>
#include <hip/hip_fp16.h>
#include <math.h>

// Problem constants
#define E     256
#define HW    1024               // 32*32
#define NTOK  8192               // B*H*W
#define NE    16384
// Screening margin: empirical f16-screen error class ~0.03-0.05 max; 0.5
// passed rounds 12-13 with absmax 0 (~10x headroom).
#define MARGIN 0.5f

typedef __attribute__((ext_vector_type(8))) _Float16 f16x8;
typedef __attribute__((ext_vector_type(4))) float    f32x4;

typedef __attribute__((address_space(3))) unsigned int       as3_u32;
typedef const __attribute__((address_space(1))) unsigned int as1_u32;

// async 16B/lane global->LDS: LDS dest = wave-uniform base + lane*16
static __device__ __forceinline__ void async_cp16(const void* g, void* l) {
    __builtin_amdgcn_global_load_lds((as1_u32*)g, (as3_u32*)l, 16, 0, 0);
}

// float -> order-preserving uint32 (no NaNs here)
__device__ __forceinline__ unsigned int f2key(float f) {
    unsigned int u = __float_as_uint(f);
    return (u & 0x80000000u) ? ~u : (u | 0x80000000u);
}
__device__ __forceinline__ float key2f(unsigned int k) {
    return __uint_as_float((k & 0x80000000u) ? (k ^ 0x80000000u) : ~k);
}
// merge sorted pair (a1,a2) into running (m1,m2): two smallest overall
__device__ __forceinline__ void kmin2(unsigned long long& m1, unsigned long long& m2,
                                      unsigned long long a1, unsigned long long a2) {
    unsigned long long lo = m1 < a1 ? m1 : a1;
    unsigned long long hi = m1 < a1 ? a1 : m1;
    unsigned long long s  = m2 < a2 ? m2 : a2;
    m1 = lo;
    m2 = hi < s ? hi : s;
}

// ---------------------------------------------------------------------------
// Kernel 1: codebook prep. Wave per row: cnorm[n] = sum(c^2) (fp32 exact),
// and B2h[n][k] = f16(c_k), K-contiguous (512 B rows).
// ---------------------------------------------------------------------------
__global__ __launch_bounds__(256) void k_prep_cb(const float* __restrict__ cb,
                                                 unsigned short* __restrict__ B2,
                                                 float* __restrict__ cnorm) {
    const int wid  = threadIdx.x >> 6;
    const int lane = threadIdx.x & 63;
    const int row  = blockIdx.x * 4 + wid;
    float4 v = *(const float4*)(cb + (size_t)row * E + lane * 4);
    float s = v.x * v.x + v.y * v.y + v.z * v.z + v.w * v.w;
#pragma unroll
    for (int off = 32; off >= 1; off >>= 1) s += __shfl_xor(s, off, 64);
    if (lane == 0) cnorm[row] = s;

    ushort4 hi4 = {__half_as_ushort(__float2half(v.x)),
                   __half_as_ushort(__float2half(v.y)),
                   __half_as_ushort(__float2half(v.z)),
                   __half_as_ushort(__float2half(v.w))};
    *(ushort4*)(B2 + (size_t)row * E + lane * 4) = hi4;   // coalesced
}

// ---------------------------------------------------------------------------
// Kernel 2: z prep with transpose. z[b][e][hw] fp32 -> A2h[m=b*1024+hw][e]
// f16. 64hw x 64e tile through padded LDS.
// ---------------------------------------------------------------------------
__global__ __launch_bounds__(256) void k_prep_z(const float* __restrict__ z,
                                                unsigned short* __restrict__ A2) {
    __shared__ float lds[64 * 65];
    const int tid = threadIdx.x;
    const int hw0 = blockIdx.x * 64;
    const int e0  = blockIdx.y * 64;
    const int b   = blockIdx.z;
#pragma unroll
    for (int r = 0; r < 16; ++r) {
        int e  = e0 + r * 4 + (tid >> 6);
        int hw = hw0 + (tid & 63);
        lds[(tid & 63) * 65 + r * 4 + (tid >> 6)] =
            z[((size_t)b * E + e) * HW + hw];
    }
    __syncthreads();
    const int row = tid & 63;          // hw within tile
    const int q   = tid >> 6;          // 16-col group
    const size_t m = (size_t)b * HW + hw0 + row;
    unsigned short* __restrict__ ph = A2 + m * E + e0 + q * 16;
#pragma unroll
    for (int g = 0; g < 4; ++g) {
        ushort4 h = {__half_as_ushort(__float2half(lds[row * 65 + q * 16 + g * 4 + 0])),
                     __half_as_ushort(__float2half(lds[row * 65 + q * 16 + g * 4 + 1])),
                     __half_as_ushort(__float2half(lds[row * 65 + q * 16 + g * 4 + 2])),
                     __half_as_ushort(__float2half(lds[row * 65 + q * 16 + g * 4 + 3]))};
        *(ushort4*)(ph + g * 4) = h;
    }
}

// ---------------------------------------------------------------------------
// Kernel 3 (pass 1): hi.hi screening GEMM.
// ROUND 14: 512-thread blocks, 8 waves, 64x32 wave tiles. Round 13 still
// spilled ~97 MB (WRITE_SIZE 109 vs 12 MB logical): 64-acc + 32-frag usage
// ~116 regs vs the (256,4) cap of 128 left no headroom. Halving the wave
// tile cuts acc to 32 + frags 24 -> ~75 regs, fitting (512,6)'s cap of 85
// -> 3 blocks/CU = 24 waves = 75% occupancy AND zero spill. Same 128x128
// block tile, BK=32, verified swizzle, f32 epilogue (j-width 2), cross-wave
// reduce over 4 wave-columns.
// ---------------------------------------------------------------------------
__global__ __launch_bounds__(512, 6) void k_mfma(
    const unsigned short* __restrict__ A2, const unsigned short* __restrict__ B2,
    const float* __restrict__ cnorm,
    unsigned long long* __restrict__ rec1, unsigned int* __restrict__ rec2)
{
    __shared__ __align__(16) unsigned short Ah[128 * 32];   // 8 KB each
    __shared__ __align__(16) unsigned short Bh[128 * 32];
    __shared__ float redv1[128 * 4];                        // 2 KB each
    __shared__ float redv2[128 * 4];
    __shared__ int   redn [128 * 4];

    const int tid  = threadIdx.x;
    const int lane = tid & 63;
    const int wave = __builtin_amdgcn_readfirstlane(tid >> 6);   // 0..7

    const int bid   = blockIdx.x;
    const int xcd   = bid & 7;
    const int loc   = bid >> 3;
    const int xtile = loc >> 4;                // 0..63 token tile (slowest)
    const int ytile = xcd * 16 + (loc & 15);   // 0..127 code chunk
    const int m0 = xtile * 128;
    const int n0 = ytile * 128;

    const int wm = (wave >> 2) * 64;           // wave row block: 0 or 64
    const int wn = (wave & 3) * 32;            // wave col block: 0/32/64/96

    // staging: each thread copies one 16B chunk of A and one of B per kc.
    // row r = wave*16 + (lane>>2); physical chunk = lane&3; source logical
    // chunk = (lane&3) ^ ((r>>1)&3) = (lane&3) ^ ((lane>>3)&3).
    const int srow  = (lane >> 2);                              // 0..15
    const int schnk = (((lane & 3) ^ ((lane >> 3) & 3)) * 16);

    f32x4 acc1[4][2];
#pragma unroll
    for (int i = 0; i < 4; ++i)
#pragma unroll
        for (int j = 0; j < 2; ++j) acc1[i][j] = (f32x4){0.f, 0.f, 0.f, 0.f};

    // read-side swizzle: physical chunk = logical(lane>>4) ^ ((row>>1)&3)
    const int pofs = (((lane >> 4) ^ ((lane >> 1) & 3)) << 4);

    for (int kc = 0; kc < 8; ++kc) {     // eight 32-half slices of E=256
        const int kb = kc * 64;
        {
            int r = wave * 16 + srow;
            size_t dofs = (size_t)(wave * 1024);
            async_cp16((const char*)A2 + (size_t)(m0 + r) * 512 + kb + schnk,
                       (char*)Ah + dofs);
            async_cp16((const char*)B2 + (size_t)(n0 + r) * 512 + kb + schnk,
                       (char*)Bh + dofs);
        }
        __syncthreads();
        f16x8 ah[4], bh[2];
#pragma unroll
        for (int i = 0; i < 4; ++i)
            ah[i] = *(const f16x8*)((const char*)Ah +
                    (wm + i * 16 + (lane & 15)) * 64 + pofs);
#pragma unroll
        for (int j = 0; j < 2; ++j)
            bh[j] = *(const f16x8*)((const char*)Bh +
                    (wn + j * 16 + (lane & 15)) * 64 + pofs);
#pragma unroll
        for (int i = 0; i < 4; ++i)
#pragma unroll
            for (int j = 0; j < 2; ++j)
                acc1[i][j] = __builtin_amdgcn_mfma_f32_16x16x32_f16(
                    ah[i], bh[j], acc1[i][j], 0, 0, 0);
        __syncthreads();
    }

    // ---- f32 epilogue: per (row) two-min over 32 cols + argmin index ------
    const int nb = n0 + wn + (lane & 15);       // lane's col base
    float cn0 = cnorm[nb], cn1 = cnorm[nb + 16];

#pragma unroll
    for (int i = 0; i < 4; ++i) {
#pragma unroll
        for (int r = 0; r < 4; ++r) {
            float d0 = fmaf(-2.f, acc1[i][0][r], cn0);
            float d1 = fmaf(-2.f, acc1[i][1][r], cn1);
            float v1 = fminf(d0, d1);
            float v2 = fmaxf(d0, d1);
#pragma unroll
            for (int off = 1; off < 16; off <<= 1) {
                float o1 = __shfl_xor(v1, off, 64);
                float o2 = __shfl_xor(v2, off, 64);
                v2 = fminf(fminf(v2, o2), fmaxf(v1, o1));
                v1 = fminf(v1, o1);
            }
            // index: smallest n with d == v1 (d1 first, d0 overrides)
            int cand = 0x7fffffff;
            if (d1 == v1) cand = nb + 16;
            if (d0 == v1) cand = nb;
#pragma unroll
            for (int off = 1; off < 16; off <<= 1)
                cand = min(cand, __shfl_xor(cand, off, 64));
            if ((lane & 15) == 0) {
                int rowl = wm + i * 16 + ((lane >> 4) << 2) + r;   // 0..127
                redv1[rowl * 4 + (wave & 3)] = v1;
                redv2[rowl * 4 + (wave & 3)] = v2;
                redn [rowl * 4 + (wave & 3)] = cand;
            }
        }
    }
    __syncthreads();
    if (tid < 128) {
        float v1 = redv1[tid * 4], v2 = redv2[tid * 4];
        int   n  = redn [tid * 4];
#pragma unroll
        for (int c = 1; c < 4; ++c) {
            float a1 = redv1[tid * 4 + c], a2 = redv2[tid * 4 + c];
            int   an = redn [tid * 4 + c];
            if (a1 < v1) { v2 = fminf(v1, a2); v1 = a1; n = an; }
            else {
                v2 = fminf(v2, a1);           // a1 itself is a competitor
                if (a1 == v1) n = min(n, an); // tie -> smallest index
            }
        }
        rec1[(size_t)(m0 + tid) * 128 + ytile] =
            ((unsigned long long)f2key(v1) << 32) | (unsigned int)n;
        rec2[(size_t)(m0 + tid) * 128 + ytile] = f2key(v2);
    }
}

// ---------------------------------------------------------------------------
// Kernel 4 (pass 2): wave per token. Coalesced [token][chunk] rec reads.
// Reduce 128 chunk records to global (best, 2nd). If 2nd >= best + MARGIN:
// done. Else rescore under-threshold chunks in exact fp32, lane-per-code
// (x staged in per-wave LDS, read back as wave-uniform broadcast).
// ---------------------------------------------------------------------------
__global__ __launch_bounds__(256) void k_pick(
    const unsigned long long* __restrict__ rec1, const unsigned int* __restrict__ rec2,
    const float* __restrict__ z, const float* __restrict__ cb,
    const float* __restrict__ cnorm, unsigned long long* __restrict__ keys)
{
    __shared__ float ldsx[4 * 256];             // per-wave x slice
    const int lane  = threadIdx.x & 63;
    const int wid   = threadIdx.x >> 6;
    const int token = blockIdx.x * 4 + wid;
    const int b  = token >> 10, hw = token & 1023;

    unsigned long long cm0 = rec1[(size_t)token * 128 + lane];        // coalesced
    unsigned long long cm1 = rec1[(size_t)token * 128 + 64 + lane];
    unsigned long long s0  = ((unsigned long long)rec2[(size_t)token * 128 + lane] << 32)
                             | 0xffffffffull;
    unsigned long long s1  = ((unsigned long long)rec2[(size_t)token * 128 + 64 + lane] << 32)
                             | 0xffffffffull;

    unsigned long long m1 = cm0, m2 = s0;
    kmin2(m1, m2, cm1, s1);
#pragma unroll
    for (int off = 1; off < 64; off <<= 1) {
        unsigned long long o1 = __shfl_xor(m1, off, 64);
        unsigned long long o2 = __shfl_xor(m2, off, 64);
        kmin2(m1, m2, o1, o2);
    }
    float d1 = key2f((unsigned int)(m1 >> 32));
    float d2 = key2f((unsigned int)(m2 >> 32));
    if (d2 >= d1 + MARGIN) {                 // certified
        if (lane == 0) keys[token] = m1;
        return;
    }

    // ---- exact fp32 rescore, lane-per-code --------------------------------
    const float thr = d1 + MARGIN;
    float* xs = ldsx + wid * 256;
    {
        const float* zp = z + (size_t)b * (E * HW) + hw;
        float4 xv;
        xv.x = zp[(size_t)(lane * 4 + 0) * HW];
        xv.y = zp[(size_t)(lane * 4 + 1) * HW];
        xv.z = zp[(size_t)(lane * 4 + 2) * HW];
        xv.w = zp[(size_t)(lane * 4 + 3) * HW];
        *(float4*)&xs[lane * 4] = xv;
    }
    unsigned long long msk0 = __ballot(key2f((unsigned int)(cm0 >> 32)) < thr);
    unsigned long long msk1 = __ballot(key2f((unsigned int)(cm1 >> 32)) < thr);

    unsigned long long best = ~0ull;
    while (msk0 | msk1) {
        int c;
        if (msk0) { c = __builtin_ctzll(msk0); msk0 &= msk0 - 1; }
        else      { c = 64 + __builtin_ctzll(msk1); msk1 &= msk1 - 1; }
        const int na = c * 128 + lane;          // lane's two codes
        const int nbr = na + 64;
        const float* ca  = cb + (size_t)na * E;
        const float* cbp = cb + (size_t)nbr * E;
        float a0 = 0.f, a1 = 0.f, a2 = 0.f, a3 = 0.f;
        float b0 = 0.f, b1 = 0.f, b2 = 0.f, b3 = 0.f;
#pragma unroll 8
        for (int kg = 0; kg < 64; ++kg) {
            float4 xv = *(const float4*)&xs[kg * 4];   // wave-uniform broadcast
            float4 va = *(const float4*)(ca  + kg * 4);
            float4 vb = *(const float4*)(cbp + kg * 4);
            a0 = fmaf(xv.x, va.x, a0); a1 = fmaf(xv.y, va.y, a1);
            a2 = fmaf(xv.z, va.z, a2); a3 = fmaf(xv.w, va.w, a3);
            b0 = fmaf(xv.x, vb.x, b0); b1 = fmaf(xv.y, vb.y, b1);
            b2 = fmaf(xv.z, vb.z, b2); b3 = fmaf(xv.w, vb.w, b3);
        }
        float da = fmaf(-2.f, (a0 + a1) + (a2 + a3), cnorm[na]);
        float db = fmaf(-2.f, (b0 + b1) + (b2 + b3), cnorm[nbr]);
        unsigned long long ka =
            ((unsigned long long)f2key(da) << 32) | (unsigned int)na;
        unsigned long long kb2 =
            ((unsigned long long)f2key(db) << 32) | (unsigned int)nbr;
        best = ka < best ? ka : best;
        best = kb2 < best ? kb2 : best;
    }
#pragma unroll
    for (int off = 1; off < 64; off <<= 1) {
        unsigned long long o = __shfl_xor(best, off, 64);
        best = o < best ? o : best;
    }
    if (lane == 0) keys[token] = best;
}

// ---------------------------------------------------------------------------
// Kernel 5: gather codebook rows -> out[B,E,H,W], LDS transpose (pad 257).
// ---------------------------------------------------------------------------
__global__ __launch_bounds__(256) void k_out(const float* __restrict__ z,
                                             const float* __restrict__ cb,
                                             const unsigned long long* __restrict__ keys,
                                             float* __restrict__ out) {
    __shared__ float xq[32 * 257];
    const int tid  = threadIdx.x;
    const int tile = blockIdx.x;                // 0..255
    const int b    = tile >> 5;
    const int hw0  = (tile & 31) << 5;          // 32 tokens per block
#pragma unroll
    for (int r = 0; r < 32; ++r) {
        int code = (int)(keys[b * HW + hw0 + r] & 0xffffffffull);  // uniform
        xq[r * 257 + tid] = cb[(size_t)code * E + tid];            // coalesced
    }
    __syncthreads();
    const int grp = tid >> 5, l = tid & 31;
#pragma unroll
    for (int j = 0; j < 32; ++j) {
        int e = grp * 32 + j;
        size_t o = (size_t)b * (E * HW) + (size_t)e * HW + hw0 + l;
        float x = z[o];
        out[o] = x + (xq[l * 257 + e] - x);
    }
}

// ---------------------------------------------------------------------------
extern "C" void kernel_launch(void* const* d_in, const int* in_sizes, int n_in,
                              void* d_out, int out_size, void* d_ws, size_t ws_size,
                              hipStream_t stream) {
    const float* z  = (const float*)d_in[0];    // [8,256,32,32]
    const float* cb = (const float*)d_in[1];    // [16384,256]
    float* out = (float*)d_out;

    // workspace layout (bytes):
    //   A2h : 8192*256*2   = 4 MB  @ 0
    //   B2h : 16384*256*2  = 8 MB  @ 4M
    //   rec1: 8192*128*8   = 8 MB  @ 12M   ([token][chunk])
    //   rec2: 8192*128*4   = 4 MB  @ 20M   ([token][chunk])
    //   cnorm: 64 KB               @ 24M
    //   keys : 64 KB               @ 24M+64K      (total 24.125 MB)
    char* ws = (char*)d_ws;
    unsigned short* A2 = (unsigned short*)ws;
    unsigned short* B2 = (unsigned short*)(ws + (size_t)4 * 1024 * 1024);
    unsigned long long* rec1 = (unsigned long long*)(ws + (size_t)12 * 1024 * 1024);
    unsigned int* rec2 = (unsigned int*)(ws + (size_t)20 * 1024 * 1024);
    float* cnorm = (float*)(ws + (size_t)24 * 1024 * 1024);
    unsigned long long* keys = (unsigned long long*)((char*)cnorm + NE * 4);

    k_prep_cb<<<NE / 4, 256, 0, stream>>>(cb, B2, cnorm);
    k_prep_z <<<dim3(16, 4, 8), 256, 0, stream>>>(z, A2);
    k_mfma   <<<8192, 512, 0, stream>>>(A2, B2, cnorm, rec1, rec2);
    k_pick   <<<NTOK / 4, 256, 0, stream>>>(rec1, rec2, z, cb, cnorm, keys);
    k_out    <<<NTOK / 32, 256, 0, stream>>>(z, cb, keys, out);
}